// Round 1
// 169.175 us; speedup vs baseline: 1.0272x; 1.0272x over previous
//
#include <hip/hip_runtime.h>
#include <cstdint>

#define BB 32
#define PP 131072
#define NEG_RATIO 3
#define NBLK 2048            // k_main blocks; 64 per batch

typedef float v4f __attribute__((ext_vector_type(4)));
typedef float v2f __attribute__((ext_vector_type(2)));

// One 16-byte partial per k_main block — plain stores, zero contention.
// (R6 lesson: same-line global atomicAdds serialize ~25 ns/op.)
struct Partial {
  float ce_all, ce_pos, sl1;
  int np;
};

// Per-batch publish record for the last-block finalize.
// ce_sel kept in double so the cross-batch sum is bit-identical to the old
// k_final (which summed (double)sum_ce_all / (double)pos+(double)ce_neg).
struct __align__(32) BatchOut {
  double ce_sel;
  float sl1, cnt, np;
  float pad;
};

struct Ws {
  Partial  part[NBLK];
  BatchOut bo[BB];
  unsigned ticket;   // zeroed by k_main block 0 each iteration (no memset node)
};

__device__ __forceinline__ float sl1sum(v4f a, v4f b) {
  float dx = fabsf(a.x - b.x), dy = fabsf(a.y - b.y),
        dz = fabsf(a.z - b.z), dw = fabsf(a.w - b.w);
  float sx = dx < 1.0f ? 0.5f * dx * dx : dx - 0.5f;
  float sy = dy < 1.0f ? 0.5f * dy * dy : dy - 0.5f;
  float sz = dz < 1.0f ? 0.5f * dz * dz : dz - 0.5f;
  float sw = dw < 1.0f ? 0.5f * dw * dw : dw - 0.5f;
  return (sx + sy) + (sz + sw);
}

__device__ __forceinline__ float ce_fast(float c0, float c1, int t) {
  float m = fmaxf(c0, c1);
  float d = fabsf(c0 - c1);
  float lse = m + __logf(1.0f + __expf(-d));
  return lse - (t ? c1 : c0);
}

// exact-ish version for the (never-taken on bench data) select path
__device__ __forceinline__ float ce_of(float c0, float c1, int t) {
  float m = fmaxf(c0, c1), mn = fminf(c0, c1);
  float lse = m + log1pf(expf(mn - m));
  return lse - (t ? c1 : c0);
}

// ---------------- K_main: fused pass, partial stores ---------------------------
// R8 evidence: __launch_bounds__(256,2) -> VGPR 24->40, 68->43 us (4.1 TB/s).
// The scheduler's occupancy-driven register target was the R1-R7 bottleneck
// (live-range shrink => ~1 load in flight => 2.5 TB/s wall). R9: notch the
// budget to 1 wave/EU (512 VGPR). R10: body untouched; only change is the
// ticket reset for the merged finish kernel.
__global__ __launch_bounds__(256, 1) void k_main(
    const v4f* __restrict__ loc, const v2f* __restrict__ cf2,
    const v4f* __restrict__ loct, const int* __restrict__ tt,
    Ws* __restrict__ ws) {
  const int tid = threadIdx.x;
  const int base = blockIdx.x * 2048;

  v4f l[8], g[8];
  v2f c[8];
  int t[8];
#pragma unroll
  for (int k = 0; k < 8; ++k) {
    const int i = base + k * 256 + tid;
    l[k] = __builtin_nontemporal_load(loc + i);   // zero-reuse stream
    g[k] = __builtin_nontemporal_load(loct + i);  // zero-reuse stream
    c[k] = __builtin_nontemporal_load(cf2 + i);   // k_select path never runs on bench data
    t[k] = __builtin_nontemporal_load(tt + i);
  }

  float a_all = 0.f, a_pos = 0.f, a_sl1 = 0.f;
  int np = 0;
#pragma unroll
  for (int k = 0; k < 8; ++k) {
    const float ce = ce_fast(c[k].x, c[k].y, t[k]);
    const float s  = sl1sum(l[k], g[k]);
    const float m  = t[k] > 0 ? 1.0f : 0.0f;
    a_all += ce;
    a_pos += m * ce;
    a_sl1 += m * s;
    np    += (t[k] > 0);
  }

#pragma unroll
  for (int off = 32; off; off >>= 1) {
    a_all += __shfl_down(a_all, off);
    a_pos += __shfl_down(a_pos, off);
    a_sl1 += __shfl_down(a_sl1, off);
    np    += __shfl_down(np, off);
  }

  __shared__ float s1[4], s2[4], s3[4];
  __shared__ int s4[4];
  const int wave = tid >> 6, lane = tid & 63;
  if (lane == 0) { s1[wave] = a_all; s2[wave] = a_pos; s3[wave] = a_sl1; s4[wave] = np; }
  __syncthreads();
  if (tid == 0) {
    Partial p;
    p.ce_all = (s1[0] + s1[1]) + (s1[2] + s1[3]);
    p.ce_pos = (s2[0] + s2[1]) + (s2[2] + s2[3]);
    p.sl1    = (s3[0] + s3[1]) + (s3[2] + s3[3]);
    p.np     = s4[0] + s4[1] + s4[2] + s4[3];
    ws->part[blockIdx.x] = p;  // plain 16B store, disjoint slot
    if (blockIdx.x == 0) ws->ticket = 0u;  // visible to k_finish via dispatch boundary
  }
}

// ---------------- K_finish: reduce + (rare) select + last-block finalize -------
// Merges the old k_reduce / k_select / k_final (3 dispatches -> 1) and removes
// the memset node. Cross-block publish uses agent-scope atomics (per-XCD L2s
// are not coherent — Guideline 16); the 32nd ticket holder folds all batches.
__global__ __launch_bounds__(256) void k_finish(
    const float2* __restrict__ conf, const int* __restrict__ conft,
    Ws* __restrict__ ws, float* __restrict__ out) {
  const int b = blockIdx.x;
  const int tid = threadIdx.x;
  const int lane = tid & 63, wave = tid >> 6;

  // ---- phase 1: fold this batch's 64 partials (bit-identical to old k_reduce)
  __shared__ int sh_np;
  float r_all = 0.f, r_pos = 0.f, r_sl1 = 0.f;
  int r_np = 0;
  if (wave == 0) {
    Partial p = ws->part[b * 64 + lane];
    r_all = p.ce_all; r_pos = p.ce_pos; r_sl1 = p.sl1; r_np = p.np;
#pragma unroll
    for (int off = 32; off; off >>= 1) {
      r_all += __shfl_down(r_all, off);
      r_pos += __shfl_down(r_pos, off);
      r_sl1 += __shfl_down(r_sl1, off);
      r_np  += __shfl_down(r_np, off);
    }
    if (lane == 0) sh_np = r_np;
  }
  __syncthreads();

  const int npos = sh_np;
  const long long M = (long long)PP - npos;
  long long k = (long long)NEG_RATIO * npos;
  if (k > PP - 1) k = PP - 1;

  // ---- phase 2: general top-k negative selection (never taken on bench data:
  // npos ~ P/2 => k = P-1 >= M). Block-uniform condition, so the internal
  // __syncthreads() are safe.
  float ce_neg_f = 0.f;
  if (k > 0 && k < M) {
    const int rowbase = b * PP;

    __shared__ unsigned hist[2048];
    __shared__ unsigned sh_prefix;
    __shared__ long long sh_kk;

    unsigned prefix = 0;
    long long kk = k;
    const int shifts[3] = {21, 10, 0};
    const int widths[3] = {11, 11, 10};

    for (int pass = 0; pass < 3; ++pass) {
      const int shift = shifts[pass], width = widths[pass];
      const unsigned mask = (1u << width) - 1u;
      for (int j = tid; j < 2048; j += 256) hist[j] = 0;
      __syncthreads();
      for (int i = tid; i < PP; i += 256) {
        const float2 c = conf[rowbase + i];
        const int t = conft[rowbase + i];
        const float score = (t > 0) ? 0.0f : ce_of(c.x, c.y, t);
        const unsigned u = __float_as_uint(score);
        const bool match = (pass == 0) || ((u >> (shift + width)) == prefix);
        if (match) atomicAdd(&hist[(u >> shift) & mask], 1u);
      }
      __syncthreads();
      if (tid == 0) {
        long long c = 0;
        int d = (int)mask;
        for (; d >= 0; --d) {
          c += hist[d];
          if (c >= kk) break;
        }
        if (d < 0) d = 0;  // safety; invariant guarantees break
        sh_prefix = (prefix << width) | (unsigned)d;
        sh_kk = kk - (c - (long long)hist[d]);
      }
      __syncthreads();
      prefix = sh_prefix;
      kk = sh_kk;
      __syncthreads();
    }

    // prefix == T bits (k-th largest score). kk = #ties to include, ascending
    // index order (stable argsort semantics).
    const unsigned Tbits = prefix;
    double local_ce = 0.0;
    __shared__ unsigned wavecnt[4];
    __shared__ long long s_rt;
    if (tid == 0) s_rt = 0;
    __syncthreads();

    for (int basei = 0; basei < PP; basei += 256) {
      const int i = basei + tid;
      const float2 c = conf[rowbase + i];
      const int t = conft[rowbase + i];
      const float ce = ce_of(c.x, c.y, t);
      const float score = (t > 0) ? 0.0f : ce;
      const unsigned u = __float_as_uint(score);
      const bool gt = u > Tbits;
      const bool eq = (u == Tbits);
      const unsigned long long bal = __ballot(eq ? 1 : 0);
      if (lane == 0) wavecnt[wave] = (unsigned)__popcll(bal);
      __syncthreads();
      long long cross = s_rt;
      for (int w = 0; w < wave; ++w) cross += wavecnt[w];
      const long long myord = cross + __popcll(bal & ((1ULL << lane) - 1ULL));
      if (gt || (eq && myord < kk)) local_ce += (double)ce;
      __syncthreads();
      if (tid == 0) s_rt += (long long)wavecnt[0] + wavecnt[1] + wavecnt[2] + wavecnt[3];
      __syncthreads();
    }

#pragma unroll
    for (int off = 32; off; off >>= 1) local_ce += __shfl_down(local_ce, off);
    __shared__ double s_ce[4];
    if (lane == 0) s_ce[wave] = local_ce;
    __syncthreads();
    if (tid == 0) ce_neg_f = (float)(s_ce[0] + s_ce[1] + s_ce[2] + s_ce[3]);
  }

  // ---- phase 3: publish this batch, 32nd arrival finalizes
  __shared__ unsigned sh_ticket;
  if (tid == 0) {
    BatchOut* bo = &ws->bo[b];
    double ce_sel;
    float cnt;
    if (k >= M) {                 // case 1: sel covers every prior
      ce_sel = (double)r_all;
      cnt = (float)PP;
    } else {
      const long long kc = k > 0 ? k : 0;
      ce_sel = (double)r_pos + (double)ce_neg_f;
      cnt = (float)(npos + (int)kc);
    }
    __hip_atomic_store(&bo->ce_sel, ce_sel, __ATOMIC_RELAXED, __HIP_MEMORY_SCOPE_AGENT);
    __hip_atomic_store(&bo->sl1, r_sl1, __ATOMIC_RELAXED, __HIP_MEMORY_SCOPE_AGENT);
    __hip_atomic_store(&bo->cnt, cnt, __ATOMIC_RELAXED, __HIP_MEMORY_SCOPE_AGENT);
    __hip_atomic_store(&bo->np, (float)npos, __ATOMIC_RELAXED, __HIP_MEMORY_SCOPE_AGENT);
    sh_ticket = __hip_atomic_fetch_add(&ws->ticket, 1u, __ATOMIC_ACQ_REL,
                                       __HIP_MEMORY_SCOPE_AGENT);
  }
  __syncthreads();

  if (sh_ticket == (unsigned)(BB - 1)) {
    // Last block: fold 32 batches. Same shuffle tree + double math as the old
    // k_final (lanes >= BB carry zeros), so the result is bit-identical.
    if (tid < 64) {
      double np_d = 0.0, ce_sel = 0.0, cnt = 0.0, sl1 = 0.0;
      if (tid < BB) {
        const BatchOut* bo = &ws->bo[tid];
        ce_sel = __hip_atomic_load(&bo->ce_sel, __ATOMIC_RELAXED, __HIP_MEMORY_SCOPE_AGENT);
        sl1 = (double)__hip_atomic_load(&bo->sl1, __ATOMIC_RELAXED, __HIP_MEMORY_SCOPE_AGENT);
        cnt = (double)__hip_atomic_load(&bo->cnt, __ATOMIC_RELAXED, __HIP_MEMORY_SCOPE_AGENT);
        np_d = (double)__hip_atomic_load(&bo->np, __ATOMIC_RELAXED, __HIP_MEMORY_SCOPE_AGENT);
      }
#pragma unroll
      for (int off = 32; off; off >>= 1) {
        np_d   += __shfl_down(np_d, off);
        ce_sel += __shfl_down(ce_sel, off);
        cnt    += __shfl_down(cnt, off);
        sl1    += __shfl_down(sl1, off);
      }
      if (tid == 0) {
        const double N = np_d;
        out[0] = (float)(sl1 / (4.0 * N * N));
        out[1] = (float)(ce_sel / cnt / N);
      }
    }
  }
}

extern "C" void kernel_launch(void* const* d_in, const int* in_sizes, int n_in,
                              void* d_out, int out_size, void* d_ws, size_t ws_size,
                              hipStream_t stream) {
  const v4f*    loc   = (const v4f*)d_in[0];
  const v2f*    cf2   = (const v2f*)d_in[1];
  const float2* conf  = (const float2*)d_in[1];
  const v4f*    loct  = (const v4f*)d_in[2];
  const int*    cnft  = (const int*)d_in[3];
  Ws* ws = (Ws*)d_ws;

  // Graph is now 2 nodes (was 5): no memset (ticket zeroed by k_main, ce_neg
  // is block-local in k_finish), and reduce/select/final merged.
  k_main<<<dim3(NBLK), dim3(256), 0, stream>>>(loc, cf2, loct, cnft, ws);
  k_finish<<<dim3(BB), dim3(256), 0, stream>>>(conf, cnft, ws, (float*)d_out);
}

// Round 7
// 168.569 us; speedup vs baseline: 1.0309x; 1.0036x over previous
//
#include <hip/hip_runtime.h>
#include <cstdint>

#define BB 32
#define PP 131072
#define NEG_RATIO 3
#define NBLK 2048            // k_main blocks; 64 per batch

typedef float v4f __attribute__((ext_vector_type(4)));
typedef float v2f __attribute__((ext_vector_type(2)));
typedef int   v4i __attribute__((ext_vector_type(4)));  // NOT HIP int4 (class type):
                                                        // nontemporal builtin needs a
                                                        // native vector type.

// One 16-byte partial per k_main block — plain stores, zero contention.
// (R6 lesson: same-line global atomicAdds serialize ~25 ns/op.)
struct Partial {
  float ce_all, ce_pos, sl1;
  int np;
};

// Per-batch publish record for the last-block finalize.
struct __align__(32) BatchOut {
  double ce_sel;
  float sl1, cnt, np;
  float pad;
};

struct Ws {
  Partial  part[NBLK];
  BatchOut bo[BB];
  unsigned ticket;   // zeroed by k_main block 0 each iteration (no memset node)
};

__device__ __forceinline__ float sl1sum(v4f a, v4f b) {
  float dx = fabsf(a.x - b.x), dy = fabsf(a.y - b.y),
        dz = fabsf(a.z - b.z), dw = fabsf(a.w - b.w);
  float sx = dx < 1.0f ? 0.5f * dx * dx : dx - 0.5f;
  float sy = dy < 1.0f ? 0.5f * dy * dy : dy - 0.5f;
  float sz = dz < 1.0f ? 0.5f * dz * dz : dz - 0.5f;
  float sw = dw < 1.0f ? 0.5f * dw * dw : dw - 0.5f;
  return (sx + sy) + (sz + sw);
}

__device__ __forceinline__ float ce_fast(float c0, float c1, int t) {
  float m = fmaxf(c0, c1);
  float d = fabsf(c0 - c1);
  float lse = m + __logf(1.0f + __expf(-d));
  return lse - (t ? c1 : c0);
}

// exact-ish version for the (never-taken on bench data) select path
__device__ __forceinline__ float ce_of(float c0, float c1, int t) {
  float m = fmaxf(c0, c1), mn = fminf(c0, c1);
  float lse = m + log1pf(expf(mn - m));
  return lse - (t ? c1 : c0);
}

// ---------------- K_main: fused pass, all-dwordx4 loads ------------------------
// R8: occupancy-driven VGPR target was the R1-R7 bottleneck (loads-in-flight).
// R9: (256,1). R11: widen the two narrow streams (conf 8B/lane, conf_t 4B/lane)
// to 16B dwordx4 and redistribute via LDS so the per-thread element assignment
// (and hence bitwise summation order) is unchanged. 38 -> 22 load instrs.
__global__ __launch_bounds__(256, 1) void k_main(
    const v4f* __restrict__ loc, const v4f* __restrict__ cf4,
    const v4f* __restrict__ loct, const v4i* __restrict__ tt4,
    Ws* __restrict__ ws) {
  const int tid = threadIdx.x;
  const int base = blockIdx.x * 2048;

  __shared__ v4f sh_c[1024];  // 16 KB: this block's 2048 conf pairs
  __shared__ v4i sh_t[512];   //  8 KB: this block's 2048 labels

  // conf as v4f: element e covers priors 2e,2e+1. Block range [base/2, base/2+1024).
  v4f c4[4];
  v4i t4[2];
#pragma unroll
  for (int k = 0; k < 4; ++k)
    c4[k] = __builtin_nontemporal_load(cf4 + (base >> 1) + k * 256 + tid);
#pragma unroll
  for (int k = 0; k < 2; ++k)
    t4[k] = __builtin_nontemporal_load(tt4 + (base >> 2) + k * 256 + tid);

  v4f l[8], g[8];
#pragma unroll
  for (int k = 0; k < 8; ++k) {
    const int i = base + k * 256 + tid;
    l[k] = __builtin_nontemporal_load(loc + i);   // zero-reuse stream
    g[k] = __builtin_nontemporal_load(loct + i);  // zero-reuse stream
  }

  // Stage conf/conf_t to LDS (stride-1 writes/reads: conflict-free; 2 lanes
  // per bank on b64/b32 reads is the free 2-way case).
#pragma unroll
  for (int k = 0; k < 4; ++k) sh_c[k * 256 + tid] = c4[k];
#pragma unroll
  for (int k = 0; k < 2; ++k) sh_t[k * 256 + tid] = t4[k];
  __syncthreads();

  const v2f* shc2 = (const v2f*)sh_c;
  const int* sht1 = (const int*)sh_t;

  float a_all = 0.f, a_pos = 0.f, a_sl1 = 0.f;
  int np = 0;
#pragma unroll
  for (int k = 0; k < 8; ++k) {
    const v2f c = shc2[k * 256 + tid];   // same prior as l[k]/g[k]: base + k*256 + tid
    const int t = sht1[k * 256 + tid];
    const float ce = ce_fast(c.x, c.y, t);
    const float s  = sl1sum(l[k], g[k]);
    const float m  = t > 0 ? 1.0f : 0.0f;
    a_all += ce;
    a_pos += m * ce;
    a_sl1 += m * s;
    np    += (t > 0);
  }

#pragma unroll
  for (int off = 32; off; off >>= 1) {
    a_all += __shfl_down(a_all, off);
    a_pos += __shfl_down(a_pos, off);
    a_sl1 += __shfl_down(a_sl1, off);
    np    += __shfl_down(np, off);
  }

  __shared__ float s1[4], s2[4], s3[4];
  __shared__ int s4[4];
  const int wave = tid >> 6, lane = tid & 63;
  if (lane == 0) { s1[wave] = a_all; s2[wave] = a_pos; s3[wave] = a_sl1; s4[wave] = np; }
  __syncthreads();
  if (tid == 0) {
    Partial p;
    p.ce_all = (s1[0] + s1[1]) + (s1[2] + s1[3]);
    p.ce_pos = (s2[0] + s2[1]) + (s2[2] + s2[3]);
    p.sl1    = (s3[0] + s3[1]) + (s3[2] + s3[3]);
    p.np     = s4[0] + s4[1] + s4[2] + s4[3];
    ws->part[blockIdx.x] = p;  // plain 16B store, disjoint slot
    if (blockIdx.x == 0) ws->ticket = 0u;  // visible to k_finish via dispatch boundary
  }
}

// ---------------- K_finish: reduce + (rare) select + last-block finalize -------
__global__ __launch_bounds__(256) void k_finish(
    const float2* __restrict__ conf, const int* __restrict__ conft,
    Ws* __restrict__ ws, float* __restrict__ out) {
  const int b = blockIdx.x;
  const int tid = threadIdx.x;
  const int lane = tid & 63, wave = tid >> 6;

  // ---- phase 1: fold this batch's 64 partials (bit-identical to old k_reduce)
  __shared__ int sh_np;
  float r_all = 0.f, r_pos = 0.f, r_sl1 = 0.f;
  int r_np = 0;
  if (wave == 0) {
    Partial p = ws->part[b * 64 + lane];
    r_all = p.ce_all; r_pos = p.ce_pos; r_sl1 = p.sl1; r_np = p.np;
#pragma unroll
    for (int off = 32; off; off >>= 1) {
      r_all += __shfl_down(r_all, off);
      r_pos += __shfl_down(r_pos, off);
      r_sl1 += __shfl_down(r_sl1, off);
      r_np  += __shfl_down(r_np, off);
    }
    if (lane == 0) sh_np = r_np;
  }
  __syncthreads();

  const int npos = sh_np;
  const long long M = (long long)PP - npos;
  long long k = (long long)NEG_RATIO * npos;
  if (k > PP - 1) k = PP - 1;

  // ---- phase 2: general top-k negative selection (never taken on bench data:
  // npos ~ P/2 => k = P-1 >= M). Block-uniform condition, internal syncs safe.
  float ce_neg_f = 0.f;
  if (k > 0 && k < M) {
    const int rowbase = b * PP;

    __shared__ unsigned hist[2048];
    __shared__ unsigned sh_prefix;
    __shared__ long long sh_kk;

    unsigned prefix = 0;
    long long kk = k;
    const int shifts[3] = {21, 10, 0};
    const int widths[3] = {11, 11, 10};

    for (int pass = 0; pass < 3; ++pass) {
      const int shift = shifts[pass], width = widths[pass];
      const unsigned mask = (1u << width) - 1u;
      for (int j = tid; j < 2048; j += 256) hist[j] = 0;
      __syncthreads();
      for (int i = tid; i < PP; i += 256) {
        const float2 c = conf[rowbase + i];
        const int t = conft[rowbase + i];
        const float score = (t > 0) ? 0.0f : ce_of(c.x, c.y, t);
        const unsigned u = __float_as_uint(score);
        const bool match = (pass == 0) || ((u >> (shift + width)) == prefix);
        if (match) atomicAdd(&hist[(u >> shift) & mask], 1u);
      }
      __syncthreads();
      if (tid == 0) {
        long long c = 0;
        int d = (int)mask;
        for (; d >= 0; --d) {
          c += hist[d];
          if (c >= kk) break;
        }
        if (d < 0) d = 0;  // safety; invariant guarantees break
        sh_prefix = (prefix << width) | (unsigned)d;
        sh_kk = kk - (c - (long long)hist[d]);
      }
      __syncthreads();
      prefix = sh_prefix;
      kk = sh_kk;
      __syncthreads();
    }

    const unsigned Tbits = prefix;
    double local_ce = 0.0;
    __shared__ unsigned wavecnt[4];
    __shared__ long long s_rt;
    if (tid == 0) s_rt = 0;
    __syncthreads();

    for (int basei = 0; basei < PP; basei += 256) {
      const int i = basei + tid;
      const float2 c = conf[rowbase + i];
      const int t = conft[rowbase + i];
      const float ce = ce_of(c.x, c.y, t);
      const float score = (t > 0) ? 0.0f : ce;
      const unsigned u = __float_as_uint(score);
      const bool gt = u > Tbits;
      const bool eq = (u == Tbits);
      const unsigned long long bal = __ballot(eq ? 1 : 0);
      if (lane == 0) wavecnt[wave] = (unsigned)__popcll(bal);
      __syncthreads();
      long long cross = s_rt;
      for (int w = 0; w < wave; ++w) cross += wavecnt[w];
      const long long myord = cross + __popcll(bal & ((1ULL << lane) - 1ULL));
      if (gt || (eq && myord < kk)) local_ce += (double)ce;
      __syncthreads();
      if (tid == 0) s_rt += (long long)wavecnt[0] + wavecnt[1] + wavecnt[2] + wavecnt[3];
      __syncthreads();
    }

#pragma unroll
    for (int off = 32; off; off >>= 1) local_ce += __shfl_down(local_ce, off);
    __shared__ double s_ce[4];
    if (lane == 0) s_ce[wave] = local_ce;
    __syncthreads();
    if (tid == 0) ce_neg_f = (float)(s_ce[0] + s_ce[1] + s_ce[2] + s_ce[3]);
  }

  // ---- phase 3: publish this batch, 32nd arrival finalizes
  __shared__ unsigned sh_ticket;
  if (tid == 0) {
    BatchOut* bo = &ws->bo[b];
    double ce_sel;
    float cnt;
    if (k >= M) {                 // case 1: sel covers every prior
      ce_sel = (double)r_all;
      cnt = (float)PP;
    } else {
      const long long kc = k > 0 ? k : 0;
      ce_sel = (double)r_pos + (double)ce_neg_f;
      cnt = (float)(npos + (int)kc);
    }
    __hip_atomic_store(&bo->ce_sel, ce_sel, __ATOMIC_RELAXED, __HIP_MEMORY_SCOPE_AGENT);
    __hip_atomic_store(&bo->sl1, r_sl1, __ATOMIC_RELAXED, __HIP_MEMORY_SCOPE_AGENT);
    __hip_atomic_store(&bo->cnt, cnt, __ATOMIC_RELAXED, __HIP_MEMORY_SCOPE_AGENT);
    __hip_atomic_store(&bo->np, (float)npos, __ATOMIC_RELAXED, __HIP_MEMORY_SCOPE_AGENT);
    sh_ticket = __hip_atomic_fetch_add(&ws->ticket, 1u, __ATOMIC_ACQ_REL,
                                       __HIP_MEMORY_SCOPE_AGENT);
  }
  __syncthreads();

  if (sh_ticket == (unsigned)(BB - 1)) {
    // Last block: fold 32 batches. Same shuffle tree + double math as the old
    // k_final (lanes >= BB carry zeros), so the result is bit-identical.
    if (tid < 64) {
      double np_d = 0.0, ce_sel = 0.0, cnt = 0.0, sl1 = 0.0;
      if (tid < BB) {
        const BatchOut* bo = &ws->bo[tid];
        ce_sel = __hip_atomic_load(&bo->ce_sel, __ATOMIC_RELAXED, __HIP_MEMORY_SCOPE_AGENT);
        sl1 = (double)__hip_atomic_load(&bo->sl1, __ATOMIC_RELAXED, __HIP_MEMORY_SCOPE_AGENT);
        cnt = (double)__hip_atomic_load(&bo->cnt, __ATOMIC_RELAXED, __HIP_MEMORY_SCOPE_AGENT);
        np_d = (double)__hip_atomic_load(&bo->np, __ATOMIC_RELAXED, __HIP_MEMORY_SCOPE_AGENT);
      }
#pragma unroll
      for (int off = 32; off; off >>= 1) {
        np_d   += __shfl_down(np_d, off);
        ce_sel += __shfl_down(ce_sel, off);
        cnt    += __shfl_down(cnt, off);
        sl1    += __shfl_down(sl1, off);
      }
      if (tid == 0) {
        const double N = np_d;
        out[0] = (float)(sl1 / (4.0 * N * N));
        out[1] = (float)(ce_sel / cnt / N);
      }
    }
  }
}

extern "C" void kernel_launch(void* const* d_in, const int* in_sizes, int n_in,
                              void* d_out, int out_size, void* d_ws, size_t ws_size,
                              hipStream_t stream) {
  const v4f*    loc   = (const v4f*)d_in[0];
  const v4f*    cf4   = (const v4f*)d_in[1];
  const float2* conf  = (const float2*)d_in[1];
  const v4f*    loct  = (const v4f*)d_in[2];
  const v4i*    tt4   = (const v4i*)d_in[3];
  const int*    cnft  = (const int*)d_in[3];
  Ws* ws = (Ws*)d_ws;

  // 2-node graph: k_main (all-x4 streaming pass) -> k_finish (reduce+finalize).
  k_main<<<dim3(NBLK), dim3(256), 0, stream>>>(loc, cf4, loct, tt4, ws);
  k_finish<<<dim3(BB), dim3(256), 0, stream>>>(conf, cnft, ws, (float*)d_out);
}